// Round 1
// baseline (1889.433 us; speedup 1.0000x reference)
//
#include <hip/hip_runtime.h>

#define NTOK 65536
#define DIMS 256
#define NCODES 4096
#define MT 128
#define NTT 128
#define KC 32

// One wave per row: out[r] = sum_d x[r][d]^2
__global__ void row_norm_kernel(const float* __restrict__ x,
                                float* __restrict__ out, int rows) {
  int wid = (blockIdx.x * blockDim.x + threadIdx.x) >> 6;
  int lane = threadIdx.x & 63;
  if (wid >= rows) return;
  const float* r = x + (size_t)wid * DIMS;
  float s = 0.f;
#pragma unroll
  for (int i = 0; i < DIMS / 64; ++i) {
    float v = r[lane + 64 * i];
    s += v * v;
  }
#pragma unroll
  for (int off = 32; off >= 1; off >>= 1) s += __shfl_down(s, off, 64);
  if (lane == 0) out[wid] = s;
}

// Fused distance-matmul + argmin + gather.
// Block: 256 threads, C-tile 128 tokens x 128 codes, 8x8 micro-tile.
// As/Bs staged transposed: As[k][m] = z[m0+m][k0+k], so inner loop reads are
// float4 (ds_read_b128) with only 2-way bank aliasing (free on gfx950).
__global__ __launch_bounds__(256) void vq_argmin_kernel(
    const float* __restrict__ z, const float* __restrict__ emb,
    const float* __restrict__ znorm, const float* __restrict__ enorm,
    float* __restrict__ out_zq, float* __restrict__ out_idx) {
  __shared__ float As[KC][MT];
  __shared__ float Bs[KC][NTT];
  __shared__ float red_v[MT][17];
  __shared__ int red_i[MT][17];

  const int t = threadIdx.x;
  const int tx = t & 15, ty = t >> 4;
  const int m0 = blockIdx.x * MT;

  int rows[8];
#pragma unroll
  for (int i = 0; i < 8; ++i)
    rows[i] = (i < 4) ? (ty * 4 + i) : (64 + ty * 4 + (i - 4));

  float zn[8];
#pragma unroll
  for (int i = 0; i < 8; ++i) zn[i] = znorm[m0 + rows[i]];

  float bestv[8];
  int besti[8];
#pragma unroll
  for (int i = 0; i < 8; ++i) {
    bestv[i] = 3.4e38f;
    besti[i] = 0;
  }

  const int lrow = t >> 1;   // 0..127: row staged by this thread
  const int lhalf = t & 1;   // which 16-dim half of the K-chunk
  const float* zsrc_base = z + (size_t)(m0 + lrow) * DIMS + lhalf * 16;

  for (int n0 = 0; n0 < NCODES; n0 += NTT) {
    float acc[8][8];
#pragma unroll
    for (int i = 0; i < 8; ++i)
#pragma unroll
      for (int j = 0; j < 8; ++j) acc[i][j] = 0.f;

    const float* esrc_base = emb + (size_t)(n0 + lrow) * DIMS + lhalf * 16;

    for (int k0 = 0; k0 < DIMS; k0 += KC) {
      __syncthreads();
      {
        const float4* s4 = (const float4*)(zsrc_base + k0);
        float4 v0 = s4[0], v1 = s4[1], v2 = s4[2], v3 = s4[3];
        int kb = lhalf * 16;
        As[kb + 0][lrow] = v0.x; As[kb + 1][lrow] = v0.y;
        As[kb + 2][lrow] = v0.z; As[kb + 3][lrow] = v0.w;
        As[kb + 4][lrow] = v1.x; As[kb + 5][lrow] = v1.y;
        As[kb + 6][lrow] = v1.z; As[kb + 7][lrow] = v1.w;
        As[kb + 8][lrow] = v2.x; As[kb + 9][lrow] = v2.y;
        As[kb + 10][lrow] = v2.z; As[kb + 11][lrow] = v2.w;
        As[kb + 12][lrow] = v3.x; As[kb + 13][lrow] = v3.y;
        As[kb + 14][lrow] = v3.z; As[kb + 15][lrow] = v3.w;
      }
      {
        const float4* s4 = (const float4*)(esrc_base + k0);
        float4 v0 = s4[0], v1 = s4[1], v2 = s4[2], v3 = s4[3];
        int kb = lhalf * 16;
        Bs[kb + 0][lrow] = v0.x; Bs[kb + 1][lrow] = v0.y;
        Bs[kb + 2][lrow] = v0.z; Bs[kb + 3][lrow] = v0.w;
        Bs[kb + 4][lrow] = v1.x; Bs[kb + 5][lrow] = v1.y;
        Bs[kb + 6][lrow] = v1.z; Bs[kb + 7][lrow] = v1.w;
        Bs[kb + 8][lrow] = v2.x; Bs[kb + 9][lrow] = v2.y;
        Bs[kb + 10][lrow] = v2.z; Bs[kb + 11][lrow] = v2.w;
        Bs[kb + 12][lrow] = v3.x; Bs[kb + 13][lrow] = v3.y;
        Bs[kb + 14][lrow] = v3.z; Bs[kb + 15][lrow] = v3.w;
      }
      __syncthreads();
#pragma unroll 8
      for (int k = 0; k < KC; ++k) {
        float4 a0 = *(const float4*)&As[k][ty * 4];
        float4 a1 = *(const float4*)&As[k][64 + ty * 4];
        float4 b0 = *(const float4*)&Bs[k][tx * 4];
        float4 b1 = *(const float4*)&Bs[k][64 + tx * 4];
        float a[8] = {a0.x, a0.y, a0.z, a0.w, a1.x, a1.y, a1.z, a1.w};
        float b[8] = {b0.x, b0.y, b0.z, b0.w, b1.x, b1.y, b1.z, b1.w};
#pragma unroll
        for (int i = 0; i < 8; ++i)
#pragma unroll
          for (int j = 0; j < 8; ++j) acc[i][j] += a[i] * b[j];
      }
    }

    // epilogue: d = (||z||^2 - 2 s) + ||e||^2 ; running argmin, first-index wins
#pragma unroll
    for (int j = 0; j < 8; ++j) {
      int col = n0 + ((j < 4) ? (tx * 4 + j) : (64 + tx * 4 + (j - 4)));
      float en = enorm[col];
#pragma unroll
      for (int i = 0; i < 8; ++i) {
        float d = (zn[i] - 2.0f * acc[i][j]) + en;
        if (d < bestv[i]) {  // strict <, cols visited ascending => first min
          bestv[i] = d;
          besti[i] = col;
        }
      }
    }
  }

  // cross-thread reduction over the 16 column-group threads per row
#pragma unroll
  for (int i = 0; i < 8; ++i) {
    red_v[rows[i]][tx] = bestv[i];
    red_i[rows[i]][tx] = besti[i];
  }
  __syncthreads();
  if (t < MT) {
    float bv = red_v[t][0];
    int bi = red_i[t][0];
#pragma unroll
    for (int c = 1; c < 16; ++c) {
      float v = red_v[t][c];
      int ix = red_i[t][c];
      if (v < bv || (v == bv && ix < bi)) {
        bv = v;
        bi = ix;
      }
    }
    out_idx[m0 + t] = (float)bi;  // tuple buffer is read back as float32
    red_i[t][16] = bi;
  }
  __syncthreads();

  // gather z_q rows: each (row, half) pair copies 128 floats
  {
    int grow = t >> 1, gh = t & 1;
    int src = red_i[grow][16];
    const float4* sp = (const float4*)(emb + (size_t)src * DIMS + gh * 128);
    float4* dp = (float4*)(out_zq + (size_t)(m0 + grow) * DIMS + gh * 128);
#pragma unroll
    for (int q = 0; q < 32; ++q) dp[q] = sp[q];
  }
}

extern "C" void kernel_launch(void* const* d_in, const int* in_sizes, int n_in,
                              void* d_out, int out_size, void* d_ws,
                              size_t ws_size, hipStream_t stream) {
  const float* z = (const float*)d_in[0];
  const float* emb = (const float*)d_in[1];
  float* out = (float*)d_out;
  float* out_zq = out;
  float* out_idx = out + (size_t)NTOK * DIMS;

  float* enorm = (float*)d_ws;          // 4096 floats
  float* znorm = enorm + NCODES;        // 65536 floats (ws usage ~272 KB)

  row_norm_kernel<<<NCODES / 4, 256, 0, stream>>>(emb, enorm, NCODES);
  row_norm_kernel<<<NTOK / 4, 256, 0, stream>>>(z, znorm, NTOK);
  vq_argmin_kernel<<<NTOK / MT, 256, 0, stream>>>(z, emb, znorm, enorm,
                                                  out_zq, out_idx);
}

// Round 2
// 982.233 us; speedup vs baseline: 1.9236x; 1.9236x over previous
//
#include <hip/hip_runtime.h>

#define NTOK 65536
#define DIMS 256
#define NCODES 4096
#define KP 24  // k32-tiles in extended K' = 768 (= [hi|hi|lo] x 8 tiles of 32)
#define MT 128
#define NT 128
#define MARGIN 0.005f
#define FLTMAX 3.402823466e38f

typedef short short8 __attribute__((ext_vector_type(8)));
typedef unsigned short us8 __attribute__((ext_vector_type(8)));
typedef float v4f __attribute__((ext_vector_type(4)));

// ---------------- ws layout (bytes) ----------------
#define ZF_OFF ((size_t)0)
#define ZF_BYTES ((size_t)NTOK * 768 * 2)    // 100663296
#define EF_OFF (ZF_OFF + ZF_BYTES)
#define EF_BYTES ((size_t)NCODES * 768 * 2)  // 6291456
#define ZN_OFF (EF_OFF + EF_BYTES)
#define ZN_BYTES ((size_t)NTOK * 4)
#define EN_OFF (ZN_OFF + ZN_BYTES)
#define EN_BYTES ((size_t)NCODES * 4)
#define CT_OFF (EN_OFF + EN_BYTES)
#define WL_OFF (CT_OFF + 256)
#define WL_BYTES ((size_t)NTOK * 4)
#define WS_REQ (WL_OFF + WL_BYTES)  // ~102.5 MB

__device__ __forceinline__ unsigned short f2bf(float f) {
  unsigned u = __float_as_uint(f);
  return (unsigned short)((u + 0x7FFFu + ((u >> 16) & 1u)) >> 16);
}
__device__ __forceinline__ float bf2f(unsigned short h) {
  return __uint_as_float(((unsigned)h) << 16);
}

__device__ __forceinline__ void async16(const unsigned short* g,
                                        unsigned short* l) {
  __builtin_amdgcn_global_load_lds(
      (const __attribute__((address_space(1))) unsigned int*)g,
      (__attribute__((address_space(3))) unsigned int*)l, 16, 0, 0);
}

// ---------------- norms: one wave per row ----------------
__global__ void row_norm_kernel(const float* __restrict__ x,
                                float* __restrict__ out, int rows) {
  int wid = (blockIdx.x * blockDim.x + threadIdx.x) >> 6;
  int lane = threadIdx.x & 63;
  if (wid >= rows) return;
  const float* r = x + (size_t)wid * DIMS;
  float s = 0.f;
#pragma unroll
  for (int i = 0; i < DIMS / 64; ++i) {
    float v = r[lane + 64 * i];
    s += v * v;
  }
#pragma unroll
  for (int off = 32; off >= 1; off >>= 1) s += __shfl_down(s, off, 64);
  if (lane == 0) out[wid] = s;
}

// ---------------- bf16 hi/lo split into MFMA-fragment-tiled layout --------
// layout: [rowblk16][k32 tile 0..23][lane64 = (r%16)+16*quad][8 bf16]
// K' segments: z -> [hi | hi | lo], e -> [hi | lo | hi] so that
// dot over K'=768 equals hi.hi + hi.lo + lo.hi.
__global__ __launch_bounds__(256) void split_frag_kernel(
    const float* __restrict__ x, unsigned short* __restrict__ xf, int off_hi2,
    int off_lo) {
  int g = blockIdx.x * 256 + threadIdx.x;
  int rl = g & 15;
  int quad = (g >> 4) & 3;
  int k32 = (g >> 6) & 7;
  int rb = g >> 9;
  int row = rb * 16 + rl;
  int k = k32 * 32 + quad * 8;
  const float* src = x + (size_t)row * DIMS + k;
  float4 f0 = *(const float4*)src;
  float4 f1 = *(const float4*)(src + 4);
  float v[8] = {f0.x, f0.y, f0.z, f0.w, f1.x, f1.y, f1.z, f1.w};
  us8 hi, lo;
#pragma unroll
  for (int i = 0; i < 8; ++i) {
    unsigned short h = f2bf(v[i]);
    hi[i] = h;
    lo[i] = f2bf(v[i] - bf2f(h));
  }
  size_t base = (size_t)rb * KP * 64 + rl + quad * 16;  // in 16B chunks
  us8* dst = (us8*)xf;
  dst[base + (size_t)k32 * 64] = hi;
  dst[base + (size_t)(k32 + off_hi2) * 64] = hi;
  dst[base + (size_t)(k32 + off_lo) * 64] = lo;
}

__global__ void zero_counter_kernel(int* c) { *c = 0; }

// ---------------- main: MFMA distance + argmin + gather ----------------
// 512 blocks x 256 thr (4 waves). Block = 128 tokens; loops 32 n0-tiles of
// 128 codes. Wave = 64x64 quadrant (wm = w>>1 rows, wn = w&1 cols).
// K' streamed in 8 steps of 96 (3 k32 tiles), single-buffered LDS.
__global__ __launch_bounds__(256, 2) void vq_mfma_kernel(
    const unsigned short* __restrict__ zf, const unsigned short* __restrict__ ef,
    const float* __restrict__ emb, const float* __restrict__ znorm,
    const float* __restrict__ enorm, float* __restrict__ out_zq,
    float* __restrict__ out_idx, int* __restrict__ wl_count,
    int* __restrict__ wl) {
  __shared__ unsigned short Abuf[24 * 512];  // 24 chunks x 1KB
  __shared__ unsigned short Bbuf[24 * 512];
  __shared__ float red_bv[2][128];
  __shared__ float red_sv[2][128];
  __shared__ int red_bi[2][128];
  __shared__ int sidx[128];
  __shared__ float sznorm[128];

  const int t = threadIdx.x;
  const int w = t >> 6, lane = t & 63;
  const int wm = w >> 1, wn = w & 1;
  const int quad = lane >> 4, l15 = lane & 15;
  const int m0 = blockIdx.x * MT;

  if (t < MT) sznorm[t] = znorm[m0 + t];

  // per-wave staging descriptors: chunks c = w*6+q (q=0..5), tbl=c/3, kk=c%3
  int aoff[6], boff[6];  // in ushort units, lane-relative
  int ldsoff[6];
#pragma unroll
  for (int q = 0; q < 6; ++q) {
    int c = w * 6 + q;
    int tbl = c / 3, kk = c - tbl * 3;
    aoff[q] = (((blockIdx.x * 8 + tbl) * KP + kk) * 64 + lane) * 8;
    boff[q] = ((tbl * KP + kk) * 64 + lane) * 8;
    ldsoff[q] = c * 512;
  }

  float bv[16], sv[16];
  int bi[16];
#pragma unroll
  for (int s = 0; s < 16; ++s) {
    bv[s] = FLTMAX;
    sv[s] = FLTMAX;
    bi[s] = 0;
  }

  for (int n0i = 0; n0i < 32; ++n0i) {
    const size_t ebase = (size_t)(n0i * 8) * KP * 512;  // ushort units
    v4f acc[4][4];
#pragma unroll
    for (int i = 0; i < 4; ++i)
#pragma unroll
      for (int j = 0; j < 4; ++j) acc[i][j] = (v4f){0.f, 0.f, 0.f, 0.f};

    for (int s = 0; s < 8; ++s) {
      const int koff = s * 1536;  // 3 k32-tiles * 512 ushort
      __syncthreads();
#pragma unroll
      for (int q = 0; q < 6; ++q) {
        async16(zf + (size_t)aoff[q] + koff, &Abuf[ldsoff[q]]);
        async16(ef + ebase + boff[q] + koff, &Bbuf[ldsoff[q]]);
      }
      __syncthreads();
#pragma unroll
      for (int ks = 0; ks < 3; ++ks) {
        short8 af[4], bfr[4];
#pragma unroll
        for (int i = 0; i < 4; ++i)
          af[i] = *(const short8*)&Abuf[(((wm * 4 + i) * 3 + ks) * 64 + lane) * 8];
#pragma unroll
        for (int j = 0; j < 4; ++j)
          bfr[j] = *(const short8*)&Bbuf[(((wn * 4 + j) * 3 + ks) * 64 + lane) * 8];
#pragma unroll
        for (int i = 0; i < 4; ++i)
#pragma unroll
          for (int j = 0; j < 4; ++j)
            acc[i][j] = __builtin_amdgcn_mfma_f32_16x16x32_bf16(
                af[i], bfr[j], acc[i][j], 0, 0, 0);
      }
    }

    // epilogue: d = (||z||^2 - 2 s) + ||e||^2, running best/second
    float znl[16];
#pragma unroll
    for (int i = 0; i < 4; ++i)
#pragma unroll
      for (int r = 0; r < 4; ++r)
        znl[i * 4 + r] = sznorm[wm * 64 + i * 16 + quad * 4 + r];

    const int n0 = n0i * NT;
#pragma unroll
    for (int j = 0; j < 4; ++j) {
      int code = n0 + wn * 64 + j * 16 + l15;
      float en = enorm[code];
#pragma unroll
      for (int i = 0; i < 4; ++i) {
#pragma unroll
        for (int r = 0; r < 4; ++r) {
          int slot = i * 4 + r;
          float d = (znl[slot] - 2.0f * acc[i][j][r]) + en;
          if (d < bv[slot]) {
            sv[slot] = bv[slot];
            bv[slot] = d;
            bi[slot] = code;
          } else if (d < sv[slot]) {
            sv[slot] = d;
          }
        }
      }
    }
  }

  // butterfly reduce across the 16 lanes sharing each token row
#pragma unroll
  for (int o = 1; o < 16; o <<= 1) {
#pragma unroll
    for (int s = 0; s < 16; ++s) {
      float ob = __shfl_xor(bv[s], o, 64);
      float os = __shfl_xor(sv[s], o, 64);
      int oi = __shfl_xor(bi[s], o, 64);
      bool take = (ob < bv[s]) || (ob == bv[s] && oi < bi[s]);
      float loser = take ? bv[s] : ob;
      float mins = fminf(sv[s], os);
      if (take) {
        bv[s] = ob;
        bi[s] = oi;
      }
      sv[s] = fminf(loser, mins);
    }
  }
  if (l15 == 0) {
#pragma unroll
    for (int i = 0; i < 4; ++i)
#pragma unroll
      for (int r = 0; r < 4; ++r) {
        int tl = wm * 64 + i * 16 + quad * 4 + r;
        red_bv[wn][tl] = bv[i * 4 + r];
        red_sv[wn][tl] = sv[i * 4 + r];
        red_bi[wn][tl] = bi[i * 4 + r];
      }
  }
  __syncthreads();
  if (t < MT) {
    float b0 = red_bv[0][t], b1 = red_bv[1][t];
    int i0 = red_bi[0][t], i1 = red_bi[1][t];
    float s0 = red_sv[0][t], s1 = red_sv[1][t];
    bool take = (b1 < b0) || (b1 == b0 && i1 < i0);
    float bb = take ? b1 : b0;
    int bidx = take ? i1 : i0;
    float ss = fminf(fminf(s0, s1), take ? b0 : b1);
    out_idx[m0 + t] = (float)bidx;
    sidx[t] = bidx;
    if (ss - bb < MARGIN) {  // uncertain: exact fp32 rescan later
      int slot = atomicAdd(wl_count, 1);
      if (slot < NTOK) wl[slot] = m0 + t;
    }
  }
  __syncthreads();
  {
    int row = t >> 1, half = t & 1;
    int src = sidx[row];
    const float4* sp = (const float4*)(emb + (size_t)src * DIMS + half * 128);
    float4* dp = (float4*)(out_zq + (size_t)(m0 + row) * DIMS + half * 128);
#pragma unroll
    for (int qq = 0; qq < 32; ++qq) dp[qq] = sp[qq];
  }
}

// ---------------- exact fp32 rescan for uncertain tokens ----------------
__global__ __launch_bounds__(256) void rescue_kernel(
    const float* __restrict__ z, const float* __restrict__ emb,
    const float* __restrict__ znorm, const float* __restrict__ enorm,
    const int* __restrict__ wl_count, const int* __restrict__ wl,
    float* __restrict__ out_zq, float* __restrict__ out_idx) {
  __shared__ __align__(16) float zrow[256];
  __shared__ float rv[256];
  __shared__ int ri[256];
  __shared__ int s_best;
  int n = *wl_count;
  if (n > NTOK) n = NTOK;
  for (int e = blockIdx.x; e < n; e += gridDim.x) {
    int token = wl[e];
    __syncthreads();
    zrow[threadIdx.x] = z[(size_t)token * DIMS + threadIdx.x];
    __syncthreads();
    float zn = znorm[token];
    float bvv = FLTMAX;
    int bii = 0;
    for (int c = threadIdx.x; c < NCODES; c += 256) {
      const float4* er = (const float4*)(emb + (size_t)c * DIMS);
      float dot = 0.f;
#pragma unroll 16
      for (int q = 0; q < 64; ++q) {
        float4 ev = er[q];
        float4 zv = *(const float4*)&zrow[q * 4];
        dot += ev.x * zv.x + ev.y * zv.y + ev.z * zv.z + ev.w * zv.w;
      }
      float d = (zn - 2.0f * dot) + enorm[c];
      if (d < bvv) {
        bvv = d;
        bii = c;
      }
    }
    rv[threadIdx.x] = bvv;
    ri[threadIdx.x] = bii;
    __syncthreads();
    if (threadIdx.x == 0) {
      float bb = rv[0];
      int bx = ri[0];
      for (int q = 1; q < 256; ++q) {
        float v = rv[q];
        int ix = ri[q];
        if (v < bb || (v == bb && ix < bx)) {
          bb = v;
          bx = ix;
        }
      }
      out_idx[token] = (float)bx;
      s_best = bx;
    }
    __syncthreads();
    out_zq[(size_t)token * DIMS + threadIdx.x] =
        emb[(size_t)s_best * DIMS + threadIdx.x];
  }
}

// ---------------- legacy fp32 path (round-1, used if ws too small) -------
__global__ __launch_bounds__(256) void vq_argmin_legacy(
    const float* __restrict__ z, const float* __restrict__ emb,
    const float* __restrict__ znorm, const float* __restrict__ enorm,
    float* __restrict__ out_zq, float* __restrict__ out_idx) {
  __shared__ float As[32][128];
  __shared__ float Bs[32][128];
  __shared__ float red_v[128][17];
  __shared__ int red_i[128][17];
  const int t = threadIdx.x;
  const int tx = t & 15, ty = t >> 4;
  const int m0 = blockIdx.x * 128;
  int rows[8];
#pragma unroll
  for (int i = 0; i < 8; ++i)
    rows[i] = (i < 4) ? (ty * 4 + i) : (64 + ty * 4 + (i - 4));
  float zn[8];
#pragma unroll
  for (int i = 0; i < 8; ++i) zn[i] = znorm[m0 + rows[i]];
  float bestv[8];
  int besti[8];
#pragma unroll
  for (int i = 0; i < 8; ++i) {
    bestv[i] = FLTMAX;
    besti[i] = 0;
  }
  const int lrow = t >> 1;
  const int lhalf = t & 1;
  const float* zsrc_base = z + (size_t)(m0 + lrow) * DIMS + lhalf * 16;
  for (int n0 = 0; n0 < NCODES; n0 += 128) {
    float acc[8][8];
#pragma unroll
    for (int i = 0; i < 8; ++i)
#pragma unroll
      for (int j = 0; j < 8; ++j) acc[i][j] = 0.f;
    const float* esrc_base = emb + (size_t)(n0 + lrow) * DIMS + lhalf * 16;
    for (int k0 = 0; k0 < DIMS; k0 += 32) {
      __syncthreads();
      {
        const float4* s4 = (const float4*)(zsrc_base + k0);
        float4 v0 = s4[0], v1 = s4[1], v2 = s4[2], v3 = s4[3];
        int kb = lhalf * 16;
        float vv[16] = {v0.x, v0.y, v0.z, v0.w, v1.x, v1.y, v1.z, v1.w,
                        v2.x, v2.y, v2.z, v2.w, v3.x, v3.y, v3.z, v3.w};
#pragma unroll
        for (int q = 0; q < 16; ++q) As[kb + q][lrow] = vv[q];
      }
      {
        const float4* s4 = (const float4*)(esrc_base + k0);
        float4 v0 = s4[0], v1 = s4[1], v2 = s4[2], v3 = s4[3];
        int kb = lhalf * 16;
        float vv[16] = {v0.x, v0.y, v0.z, v0.w, v1.x, v1.y, v1.z, v1.w,
                        v2.x, v2.y, v2.z, v2.w, v3.x, v3.y, v3.z, v3.w};
#pragma unroll
        for (int q = 0; q < 16; ++q) Bs[kb + q][lrow] = vv[q];
      }
      __syncthreads();
#pragma unroll 8
      for (int k = 0; k < 32; ++k) {
        float4 a0 = *(const float4*)&As[k][ty * 4];
        float4 a1 = *(const float4*)&As[k][64 + ty * 4];
        float4 b0 = *(const float4*)&Bs[k][tx * 4];
        float4 b1 = *(const float4*)&Bs[k][64 + tx * 4];
        float a[8] = {a0.x, a0.y, a0.z, a0.w, a1.x, a1.y, a1.z, a1.w};
        float b[8] = {b0.x, b0.y, b0.z, b0.w, b1.x, b1.y, b1.z, b1.w};
#pragma unroll
        for (int i = 0; i < 8; ++i)
#pragma unroll
          for (int j = 0; j < 8; ++j) acc[i][j] += a[i] * b[j];
      }
    }
#pragma unroll
    for (int j = 0; j < 8; ++j) {
      int col = n0 + ((j < 4) ? (tx * 4 + j) : (64 + tx * 4 + (j - 4)));
      float en = enorm[col];
#pragma unroll
      for (int i = 0; i < 8; ++i) {
        float d = (zn[i] - 2.0f * acc[i][j]) + en;
        if (d < bestv[i]) {
          bestv[i] = d;
          besti[i] = col;
        }
      }
    }
  }
#pragma unroll
  for (int i = 0; i < 8; ++i) {
    red_v[rows[i]][tx] = bestv[i];
    red_i[rows[i]][tx] = besti[i];
  }
  __syncthreads();
  if (t < 128) {
    float bvv = red_v[t][0];
    int bii = red_i[t][0];
#pragma unroll
    for (int c = 1; c < 16; ++c) {
      float v = red_v[t][c];
      int ix = red_i[t][c];
      if (v < bvv || (v == bvv && ix < bii)) {
        bvv = v;
        bii = ix;
      }
    }
    out_idx[m0 + t] = (float)bii;
    red_i[t][16] = bii;
  }
  __syncthreads();
  {
    int grow = t >> 1, gh = t & 1;
    int src = red_i[grow][16];
    const float4* sp = (const float4*)(emb + (size_t)src * DIMS + gh * 128);
    float4* dp = (float4*)(out_zq + (size_t)(m0 + grow) * DIMS + gh * 128);
#pragma unroll
    for (int q = 0; q < 32; ++q) dp[q] = sp[q];
  }
}

extern "C" void kernel_launch(void* const* d_in, const int* in_sizes, int n_in,
                              void* d_out, int out_size, void* d_ws,
                              size_t ws_size, hipStream_t stream) {
  const float* z = (const float*)d_in[0];
  const float* emb = (const float*)d_in[1];
  float* out = (float*)d_out;
  float* out_zq = out;
  float* out_idx = out + (size_t)NTOK * DIMS;

  if (ws_size >= WS_REQ) {
    char* ws = (char*)d_ws;
    unsigned short* zf = (unsigned short*)(ws + ZF_OFF);
    unsigned short* ef = (unsigned short*)(ws + EF_OFF);
    float* znorm = (float*)(ws + ZN_OFF);
    float* enorm = (float*)(ws + EN_OFF);
    int* wl_count = (int*)(ws + CT_OFF);
    int* wl = (int*)(ws + WL_OFF);

    split_frag_kernel<<<NTOK / 8, 256, 0, stream>>>(z, zf, 8, 16);
    split_frag_kernel<<<NCODES / 8, 256, 0, stream>>>(emb, ef, 16, 8);
    row_norm_kernel<<<NCODES / 4, 256, 0, stream>>>(emb, enorm, NCODES);
    row_norm_kernel<<<NTOK / 4, 256, 0, stream>>>(z, znorm, NTOK);
    zero_counter_kernel<<<1, 1, 0, stream>>>(wl_count);
    vq_mfma_kernel<<<NTOK / MT, 256, 0, stream>>>(zf, ef, emb, znorm, enorm,
                                                  out_zq, out_idx, wl_count, wl);
    rescue_kernel<<<128, 256, 0, stream>>>(z, emb, znorm, enorm, wl_count, wl,
                                           out_zq, out_idx);
  } else {
    float* enorm = (float*)d_ws;
    float* znorm = enorm + NCODES;
    row_norm_kernel<<<NCODES / 4, 256, 0, stream>>>(emb, enorm, NCODES);
    row_norm_kernel<<<NTOK / 4, 256, 0, stream>>>(z, znorm, NTOK);
    vq_argmin_legacy<<<NTOK / 128, 256, 0, stream>>>(z, emb, znorm, enorm,
                                                     out_zq, out_idx);
  }
}